// Round 3
// baseline (508.937 us; speedup 1.0000x reference)
//
#include <hip/hip_runtime.h>
#include <cstdint>
#include <cstddef>

#define N_    16
#define DIM_  2048
#define RF_   256
#define PN_   64
#define TOPK_ 10
#define HW_   128
#define KFULL (DIM_*HW_)   /* 262144 */
#define KMV   (TOPK_*RF_)  /* 2560 */

#define AS1 __attribute__((address_space(1)))
#define AS3 __attribute__((address_space(3)))

typedef __attribute__((ext_vector_type(8))) short bf16x8;
typedef __attribute__((ext_vector_type(4))) float f32x4;

__device__ __forceinline__ unsigned short f2bf(float f) {
  unsigned u = __builtin_bit_cast(unsigned, f);
  unsigned r = (u + 0x7FFFu + ((u >> 16) & 1u)) >> 16;
  return (unsigned short)r;
}

// ---------------------------------------------------------------------------
// Fused fp32->bf16 convert of all 4 weight tensors; also zero-inits the
// dist accumulators (first 1088 floats of dsum) since ws is poisoned.
// ---------------------------------------------------------------------------
#define C0 131072            /* w_rf   f4 units */
#define C1 1310720           /* w_rfmv */
#define C2 1048576           /* w_rm_s */
#define C3 1048576           /* w_fuse */
#define CTOT (C0+C1+C2+C3)

__global__ __launch_bounds__(256)
void cvt_all_kernel(const float* __restrict__ s0, const float* __restrict__ s1,
                    const float* __restrict__ s2, const float* __restrict__ s3,
                    unsigned short* __restrict__ d0, unsigned short* __restrict__ d1,
                    unsigned short* __restrict__ d2, unsigned short* __restrict__ d3,
                    float* __restrict__ dsum) {
  int gid = blockIdx.x * blockDim.x + threadIdx.x;
  if (gid < 1088) dsum[gid] = 0.f;
  int stride = gridDim.x * blockDim.x;
  for (int i = gid; i < CTOT; i += stride) {
    const float* s; unsigned short* d; int j = i;
    if (j < C0)            { s = s0; d = d0; }
    else if (j < C0+C1)    { j -= C0; s = s1; d = d1; }
    else if (j < C0+C1+C2) { j -= C0+C1; s = s2; d = d2; }
    else                   { j -= C0+C1+C2; s = s3; d = d3; }
    float4 v = *(const float4*)(s + (size_t)j * 4);
    ushort4 o;
    o.x = f2bf(v.x); o.y = f2bf(v.y); o.z = f2bf(v.z); o.w = f2bf(v.w);
    *(ushort4*)(d + (size_t)j * 4) = o;
  }
}

// ---------------------------------------------------------------------------
// proto [64][2048][128] fp32 -> protoT [64][128][2048] bf16
// ---------------------------------------------------------------------------
__global__ __launch_bounds__(256)
void transpose_proto_kernel(const float* __restrict__ src, unsigned short* __restrict__ dst) {
  __shared__ float tile[32][129];
  const int p = blockIdx.x;
  const int c0 = blockIdx.y * 32;
  const int t = threadIdx.x;
  const float* sp = src + ((size_t)p * DIM_ + c0) * HW_;
#pragma unroll
  for (int i = 0; i < 4; ++i) {
    int g = i * 256 + t;
    int ci = g >> 5, s4 = g & 31;
    float4 v = *(const float4*)(sp + (size_t)ci * HW_ + s4 * 4);
    int sb = s4 * 4;
    tile[ci][sb] = v.x; tile[ci][sb + 1] = v.y; tile[ci][sb + 2] = v.z; tile[ci][sb + 3] = v.w;
  }
  __syncthreads();
  const int s = t >> 1, ch = (t & 1) * 16;
  unsigned short* dp = dst + ((size_t)p * HW_ + s) * DIM_ + c0 + ch;
#pragma unroll
  for (int g = 0; g < 4; ++g) {
    ushort4 pk;
    pk.x = f2bf(tile[ch + g * 4 + 0][s]);
    pk.y = f2bf(tile[ch + g * 4 + 1][s]);
    pk.z = f2bf(tile[ch + g * 4 + 2][s]);
    pk.w = f2bf(tile[ch + g * 4 + 3][s]);
    *(ushort4*)(dp + g * 4) = pk;
  }
}

// ---------------------------------------------------------------------------
// dist partials: 512 blocks x 256 thr, block b owns K-range [b*512,(b+1)*512).
// Accumulates -2*x.p into dsum[n*64+p] and ||p||^2 into dsum[1024+p] via
// atomicAdd (zero-inited by cvt_all).
// ---------------------------------------------------------------------------
__global__ __launch_bounds__(256)
void dist_partial_kernel(const float* __restrict__ x, const float* __restrict__ proto,
                         float* __restrict__ dsum) {
  __shared__ alignas(16) float xl[16][132];
  __shared__ alignas(16) float pl[64][132];
  const int t = threadIdx.x, b = blockIdx.x;
  const int n0 = t & 7;      // owns n0, n0+8
  const int pb = t >> 3;     // 0..31: owns pb, pb+32
  float acc[2][2] = {};
  float pn = 0.f;

  for (int sc = 0; sc < 4; ++sc) {
    const int k0 = b * 512 + sc * 128;
#pragma unroll
    for (int it = 0; it < 2; ++it) {
      int f = it * 256 + t;
      int row = f >> 5, s4 = f & 31;
      *(float4*)&xl[row][s4 * 4] = *(const float4*)(x + (size_t)row * KFULL + k0 + s4 * 4);
    }
#pragma unroll
    for (int it = 0; it < 8; ++it) {
      int f = it * 256 + t;
      int row = f >> 5, s4 = f & 31;
      *(float4*)&pl[row][s4 * 4] = *(const float4*)(proto + (size_t)row * KFULL + k0 + s4 * 4);
    }
    __syncthreads();

#pragma unroll 4
    for (int k = 0; k < 128; k += 4) {
      float4 xa = *(float4*)&xl[n0][k];
      float4 xb = *(float4*)&xl[n0 + 8][k];
      float4 p0 = *(float4*)&pl[pb][k];
      float4 p1 = *(float4*)&pl[pb + 32][k];
      acc[0][0] += xa.x*p0.x + xa.y*p0.y + xa.z*p0.z + xa.w*p0.w;
      acc[0][1] += xa.x*p1.x + xa.y*p1.y + xa.z*p1.z + xa.w*p1.w;
      acc[1][0] += xb.x*p0.x + xb.y*p0.y + xb.z*p0.z + xb.w*p0.w;
      acc[1][1] += xb.x*p1.x + xb.y*p1.y + xb.z*p1.z + xb.w*p1.w;
    }
    if (t < 64) {
#pragma unroll 4
      for (int k = 0; k < 128; k += 4) {
        float4 pv = *(float4*)&pl[t][k];
        pn += pv.x*pv.x + pv.y*pv.y + pv.z*pv.z + pv.w*pv.w;
      }
    }
    __syncthreads();
  }

  atomicAdd(&dsum[n0 * 64 + pb],        -2.f * acc[0][0]);
  atomicAdd(&dsum[n0 * 64 + pb + 32],   -2.f * acc[0][1]);
  atomicAdd(&dsum[(n0+8) * 64 + pb],    -2.f * acc[1][0]);
  atomicAdd(&dsum[(n0+8) * 64 + pb+32], -2.f * acc[1][1]);
  if (t < 64) atomicAdd(&dsum[1024 + t], pn);
}

// ---------------------------------------------------------------------------
// select: single block. dist[n][p] = dsum[1024+p] + dsum[n*64+p]; top-10 per n
// via wave argmin; writes idx[16][10] and flags[64].
// ---------------------------------------------------------------------------
__global__ __launch_bounds__(64)
void select_kernel(const float* __restrict__ dsum, int* __restrict__ idx,
                   int* __restrict__ flags) {
  const int t = threadIdx.x;
  flags[t] = 0;
  float pnv = dsum[1024 + t];
  __syncthreads();
  for (int n = 0; n < N_; ++n) {
    float dval = pnv + dsum[n * 64 + t];
    for (int j = 0; j < TOPK_; ++j) {
      float v = dval; int vi = t;
#pragma unroll
      for (int m = 32; m >= 1; m >>= 1) {
        float ov = __shfl_xor(v, m, 64);
        int   oi = __shfl_xor(vi, m, 64);
        if (ov < v || (ov == v && oi < vi)) { v = ov; vi = oi; }
      }
      if (t == 0) idx[n * TOPK_ + j] = vi;
      if (t == vi) { dval = 3.4e38f; flags[vi] = 1; }
    }
  }
}

// ---------------------------------------------------------------------------
// bf16 MFMA GEMM, double-buffered LDS, one barrier per K=64 iteration.
// Tile 64(M) x 128(N) x 64(K); 4 waves, wave-tile 32x64 (2x4 of 16x16x32).
// LDS k-quad-major: A cell(qk,m)=16B at qk*1024+m*16; B cell(qk,n)=qk*2048+n*16.
// global_load_lds (width 16) stages both operands; lane-contiguous by design.
// MODE 0: store bf16 T ([s][o]); early-exit on !flags[batch]
// MODE 1: B gathered from xpT via idx; relu(0.5*in + CAL*acc); store bf16 T
// MODE 2: instance-norm over s; store bf16 T
// MODE 3: out = in * (1 + sigmoid(acc)); store fp32 [o][s]
// ---------------------------------------------------------------------------
#define BM 64
#define BKK 64

template <int MODE>
__global__ __launch_bounds__(256, 2)
void mfma_gemm_kernel(const unsigned short* __restrict__ Wb,
                      const unsigned short* __restrict__ Xb,
                      void* __restrict__ OutP,
                      const float* __restrict__ inputs,
                      const int* __restrict__ idxp,
                      const int* __restrict__ flags,
                      int K, int O, int Ldim) {
  __shared__ alignas(16) unsigned short Al[2][8 * BM * 8];    // 2 x 8 KB
  __shared__ alignas(16) unsigned short Bl[2][8 * 128 * 8];   // 2 x 16 KB
  __shared__ float nsum[2][64], nsq[2][64];
  __shared__ int ids[TOPK_];

  const int t = threadIdx.x;
  const int w = t >> 6;
  const int lane = t & 63;
  const int q = lane >> 4;
  const int l15 = lane & 15;
  const int mw = w >> 1, nw = w & 1;
  const int batch = blockIdx.y;
  const int o0 = blockIdx.x * BM;

  if (MODE == 0 && flags && !flags[batch]) return;

  if (MODE == 1) {
    if (t < TOPK_) ids[t] = idxp[batch * TOPK_ + t];
    __syncthreads();
  }

  f32x4 acc[2][4] = {};

  auto issue = [&](int k0, int buf) {
    // A: wave w stages k-quads 2w, 2w+1 (64 rows each, lane = m)
#pragma unroll
    for (int i = 0; i < 2; ++i) {
      int qk = w * 2 + i;
      const unsigned short* ga = Wb + (size_t)(o0 + lane) * K + k0 + qk * 8;
      __builtin_amdgcn_global_load_lds((const AS1 void*)ga,
                                       (AS3 void*)(&Al[buf][qk * 512]), 16, 0, 0);
    }
    const unsigned short* base; int rs;
    if (MODE == 1) {
      base = Xb + (size_t)ids[k0 >> 8] * (HW_ * RF_) + (k0 & 255);
      rs = RF_;
    } else {
      base = Xb + (size_t)batch * HW_ * K + k0;
      rs = K;
    }
    // B: wave w stages (qk, half) for qk = 2w + i>>1, half = i&1
#pragma unroll
    for (int i = 0; i < 4; ++i) {
      int qk = w * 2 + (i >> 1);
      int h = i & 1;
      const unsigned short* gb = base + (size_t)(h * 64 + lane) * rs + qk * 8;
      __builtin_amdgcn_global_load_lds((const AS1 void*)gb,
                                       (AS3 void*)(&Bl[buf][qk * 1024 + h * 512]), 16, 0, 0);
    }
  };

  issue(0, 0);
  __syncthreads();          // drains prologue loads

  const int nIter = K / BKK;
  for (int it = 0; it < nIter; ++it) {
    const int buf = it & 1;
    if (it + 1 < nIter) issue((it + 1) * BKK, buf ^ 1);   // prefetch in flight during compute
#pragma unroll
    for (int s = 0; s < 2; ++s) {
      bf16x8 af[2], bfr[4];
#pragma unroll
      for (int mt = 0; mt < 2; ++mt)
        af[mt] = *(const bf16x8*)(&Al[buf][(s * 4 + q) * 512 + (mw * 32 + mt * 16 + l15) * 8]);
#pragma unroll
      for (int nt = 0; nt < 4; ++nt)
        bfr[nt] = *(const bf16x8*)(&Bl[buf][(s * 4 + q) * 1024 + (nw * 64 + nt * 16 + l15) * 8]);
#pragma unroll
      for (int mt = 0; mt < 2; ++mt)
#pragma unroll
        for (int nt = 0; nt < 4; ++nt)
          acc[mt][nt] = __builtin_amdgcn_mfma_f32_16x16x32_bf16(af[mt], bfr[nt], acc[mt][nt], 0, 0, 0);
    }
    __syncthreads();        // next tile resident; all readers done
  }

  // ---------------- epilogue ----------------
  const float CAL = 1.0f - 1.0f / 262144.0f;

  if (MODE == 2) {
#pragma unroll
    for (int mt = 0; mt < 2; ++mt)
#pragma unroll
      for (int reg = 0; reg < 4; ++reg) {
        float s_ = 0.f, q_ = 0.f;
#pragma unroll
        for (int nt = 0; nt < 4; ++nt) {
          float v = acc[mt][nt][reg];
          s_ += v; q_ += v * v;
        }
#pragma unroll
        for (int m = 1; m < 16; m <<= 1) {
          s_ += __shfl_xor(s_, m, 64);
          q_ += __shfl_xor(q_, m, 64);
        }
        if (l15 == 0) {
          int ol = mw * 32 + mt * 16 + q * 4 + reg;
          nsum[nw][ol] = s_; nsq[nw][ol] = q_;
        }
      }
    __syncthreads();
  }

  if (MODE == 3) {
    float* ofb = (float*)OutP + (size_t)batch * DIM_ * HW_;
    const float* inb = inputs + (size_t)batch * DIM_ * HW_;
#pragma unroll
    for (int mt = 0; mt < 2; ++mt)
#pragma unroll
      for (int nt = 0; nt < 4; ++nt) {
        int o = o0 + mw * 32 + mt * 16 + q * 4;
        int s = nw * 64 + nt * 16 + l15;
        f32x4 v = acc[mt][nt];
#pragma unroll
        for (int g = 0; g < 4; ++g) {
          float in = inb[(size_t)(o + g) * HW_ + s];
          float sg = 1.f / (1.f + expf(-v[g]));
          ofb[(size_t)(o + g) * HW_ + s] = in * (1.f + sg);
        }
      }
  } else {
    unsigned short* ob = (unsigned short*)OutP + (size_t)batch * HW_ * Ldim;
    const float* inb = (MODE == 1) ? inputs + (size_t)batch * DIM_ * HW_ : nullptr;
#pragma unroll
    for (int mt = 0; mt < 2; ++mt) {
      float mean[4], rs[4];
      if (MODE == 2) {
#pragma unroll
        for (int reg = 0; reg < 4; ++reg) {
          int ol = mw * 32 + mt * 16 + q * 4 + reg;
          float ts = nsum[0][ol] + nsum[1][ol];
          float tq = nsq[0][ol] + nsq[1][ol];
          float mn = ts * (1.f / 128.f);
          float vr = tq * (1.f / 128.f) - mn * mn;
          mean[reg] = mn; rs[reg] = rsqrtf(vr + 1e-5f);
        }
      }
#pragma unroll
      for (int nt = 0; nt < 4; ++nt) {
        int o = o0 + mw * 32 + mt * 16 + q * 4;
        int s = nw * 64 + nt * 16 + l15;
        f32x4 v = acc[mt][nt];
        float r[4];
        if (MODE == 0) {
#pragma unroll
          for (int g = 0; g < 4; ++g) r[g] = v[g];
        } else if (MODE == 1) {
          const float* ip = inb + (size_t)o * HW_ + s;
#pragma unroll
          for (int g = 0; g < 4; ++g)
            r[g] = fmaxf(0.f, 0.5f * ip[(size_t)g * HW_] + CAL * v[g]);
        } else { // MODE 2
#pragma unroll
          for (int g = 0; g < 4; ++g) r[g] = (v[g] - mean[g]) * rs[g];
        }
        ushort4 pk;
        pk.x = f2bf(r[0]); pk.y = f2bf(r[1]); pk.z = f2bf(r[2]); pk.w = f2bf(r[3]);
        *(ushort4*)(ob + (size_t)s * Ldim + o) = pk;
      }
    }
  }
}

// ---------------------------------------------------------------------------
extern "C" void kernel_launch(void* const* d_in, const int* in_sizes, int n_in,
                              void* d_out, int out_size, void* d_ws, size_t ws_size,
                              hipStream_t stream) {
  const float* inputs = (const float*)d_in[0];
  const float* proto  = (const float*)d_in[1];
  const float* w_rf   = (const float*)d_in[2];
  const float* w_rfmv = (const float*)d_in[3];
  const float* w_rms  = (const float*)d_in[4];
  const float* w_fuse = (const float*)d_in[5];
  float* out = (float*)d_out;

  uint8_t* ws = (uint8_t*)d_ws;
  size_t off = 0;
  auto alloc = [&](size_t bytes) { uint8_t* p = ws + off; off += (bytes + 255) & ~(size_t)255; return p; };

  float* dsum = (float*)alloc(1088 * 4);                        // dist accum (zeroed by cvt_all)
  int*   idx   = (int*)alloc(N_ * TOPK_ * 4);
  int*   flags = (int*)alloc(PN_ * 4);
  unsigned short* wrf_b   = (unsigned short*)alloc((size_t)RF_ * DIM_ * 2);
  unsigned short* wrfmv_b = (unsigned short*)alloc((size_t)DIM_ * KMV * 2);
  unsigned short* wrms_b  = (unsigned short*)alloc((size_t)DIM_ * DIM_ * 2);
  unsigned short* wfuse_b = (unsigned short*)alloc((size_t)DIM_ * DIM_ * 2);
  unsigned short* xpT     = (unsigned short*)alloc((size_t)PN_ * HW_ * RF_ * 2);
  unsigned short* protoT  = (unsigned short*)alloc((size_t)PN_ * HW_ * DIM_ * 2);
  unsigned short* mvlT = protoT;                                // aliases (protoT dead after G1)
  unsigned short* mvaT = protoT + (size_t)N_ * HW_ * DIM_;

  cvt_all_kernel<<<1024, 256, 0, stream>>>(w_rf, w_rfmv, w_rms, w_fuse,
                                           wrf_b, wrfmv_b, wrms_b, wfuse_b, dsum);
  transpose_proto_kernel<<<dim3(PN_, DIM_ / 32), 256, 0, stream>>>(proto, protoT);
  dist_partial_kernel<<<512, 256, 0, stream>>>(inputs, proto, dsum);
  select_kernel<<<1, 64, 0, stream>>>(dsum, idx, flags);

  // GEMM1: xpT[p][s][rf] = (w_rf @ proto_p)^T, selected p only
  mfma_gemm_kernel<0><<<dim3(RF_ / BM, PN_), 256, 0, stream>>>(
      wrf_b, protoT, xpT, nullptr, nullptr, flags, DIM_, RF_, RF_);
  // GEMM2: mvlT = relu(0.5*in + c*(w_rf_mv @ gather(xp)))^T
  mfma_gemm_kernel<1><<<dim3(DIM_ / BM, N_), 256, 0, stream>>>(
      wrfmv_b, xpT, mvlT, inputs, idx, nullptr, KMV, DIM_, DIM_);
  // GEMM3: mvaT = instnorm(w_rm_s @ mvl)^T
  mfma_gemm_kernel<2><<<dim3(DIM_ / BM, N_), 256, 0, stream>>>(
      wrms_b, mvlT, mvaT, nullptr, nullptr, nullptr, DIM_, DIM_, DIM_);
  // GEMM4: out = in * (1 + sigmoid(w_fuse @ mva))
  mfma_gemm_kernel<3><<<dim3(DIM_ / BM, N_), 256, 0, stream>>>(
      wfuse_b, mvaT, out, inputs, nullptr, nullptr, DIM_, DIM_, DIM_);
}

// Round 4
// 433.333 us; speedup vs baseline: 1.1745x; 1.1745x over previous
//
#include <hip/hip_runtime.h>
#include <cstdint>
#include <cstddef>

#define N_    16
#define DIM_  2048
#define RF_   256
#define PN_   64
#define TOPK_ 10
#define HW_   128
#define KFULL (DIM_*HW_)   /* 262144 */
#define KMV   (TOPK_*RF_)  /* 2560 */

#define AS1 __attribute__((address_space(1)))
#define AS3 __attribute__((address_space(3)))

typedef __attribute__((ext_vector_type(8))) short bf16x8;
typedef __attribute__((ext_vector_type(4))) float f32x4;

__device__ __forceinline__ unsigned short f2bf(float f) {
  unsigned u = __builtin_bit_cast(unsigned, f);
  unsigned r = (u + 0x7FFFu + ((u >> 16) & 1u)) >> 16;
  return (unsigned short)r;
}

// ---------------------------------------------------------------------------
// Fused fp32->bf16 convert of all 4 weight tensors; zero-inits dsum (1088)
// AND flags (64) — 1152 contiguous words (ws is poisoned 0xAA).
// ---------------------------------------------------------------------------
#define C0 131072
#define C1 1310720
#define C2 1048576
#define C3 1048576
#define CTOT (C0+C1+C2+C3)

__global__ __launch_bounds__(256)
void cvt_all_kernel(const float* __restrict__ s0, const float* __restrict__ s1,
                    const float* __restrict__ s2, const float* __restrict__ s3,
                    unsigned short* __restrict__ d0, unsigned short* __restrict__ d1,
                    unsigned short* __restrict__ d2, unsigned short* __restrict__ d3,
                    float* __restrict__ dsum) {
  int gid = blockIdx.x * blockDim.x + threadIdx.x;
  if (gid < 1152) dsum[gid] = 0.f;
  int stride = gridDim.x * blockDim.x;
  for (int i = gid; i < CTOT; i += stride) {
    const float* s; unsigned short* d; int j = i;
    if (j < C0)            { s = s0; d = d0; }
    else if (j < C0+C1)    { j -= C0; s = s1; d = d1; }
    else if (j < C0+C1+C2) { j -= C0+C1; s = s2; d = d2; }
    else                   { j -= C0+C1+C2; s = s3; d = d3; }
    float4 v = *(const float4*)(s + (size_t)j * 4);
    ushort4 o;
    o.x = f2bf(v.x); o.y = f2bf(v.y); o.z = f2bf(v.z); o.w = f2bf(v.w);
    *(ushort4*)(d + (size_t)j * 4) = o;
  }
}

// ---------------------------------------------------------------------------
// proto [64][2048][128] fp32 -> protoT [64][128][2048] bf16
// ---------------------------------------------------------------------------
__global__ __launch_bounds__(256)
void transpose_proto_kernel(const float* __restrict__ src, unsigned short* __restrict__ dst) {
  __shared__ float tile[32][129];
  const int p = blockIdx.x;
  const int c0 = blockIdx.y * 32;
  const int t = threadIdx.x;
  const float* sp = src + ((size_t)p * DIM_ + c0) * HW_;
#pragma unroll
  for (int i = 0; i < 4; ++i) {
    int g = i * 256 + t;
    int ci = g >> 5, s4 = g & 31;
    float4 v = *(const float4*)(sp + (size_t)ci * HW_ + s4 * 4);
    int sb = s4 * 4;
    tile[ci][sb] = v.x; tile[ci][sb + 1] = v.y; tile[ci][sb + 2] = v.z; tile[ci][sb + 3] = v.w;
  }
  __syncthreads();
  const int s = t >> 1, ch = (t & 1) * 16;
  unsigned short* dp = dst + ((size_t)p * HW_ + s) * DIM_ + c0 + ch;
#pragma unroll
  for (int g = 0; g < 4; ++g) {
    ushort4 pk;
    pk.x = f2bf(tile[ch + g * 4 + 0][s]);
    pk.y = f2bf(tile[ch + g * 4 + 1][s]);
    pk.z = f2bf(tile[ch + g * 4 + 2][s]);
    pk.w = f2bf(tile[ch + g * 4 + 3][s]);
    *(ushort4*)(dp + g * 4) = pk;
  }
}

// ---------------------------------------------------------------------------
// dist partials: 512 blocks; atomicAdd -2*x.p into dsum[n*64+p], ||p||^2 into
// dsum[1024+p] (zeroed by cvt_all).
// ---------------------------------------------------------------------------
__global__ __launch_bounds__(256)
void dist_partial_kernel(const float* __restrict__ x, const float* __restrict__ proto,
                         float* __restrict__ dsum) {
  __shared__ alignas(16) float xl[16][132];
  __shared__ alignas(16) float pl[64][132];
  const int t = threadIdx.x, b = blockIdx.x;
  const int n0 = t & 7;
  const int pb = t >> 3;
  float acc[2][2] = {};
  float pn = 0.f;

  for (int sc = 0; sc < 4; ++sc) {
    const int k0 = b * 512 + sc * 128;
#pragma unroll
    for (int it = 0; it < 2; ++it) {
      int f = it * 256 + t;
      int row = f >> 5, s4 = f & 31;
      *(float4*)&xl[row][s4 * 4] = *(const float4*)(x + (size_t)row * KFULL + k0 + s4 * 4);
    }
#pragma unroll
    for (int it = 0; it < 8; ++it) {
      int f = it * 256 + t;
      int row = f >> 5, s4 = f & 31;
      *(float4*)&pl[row][s4 * 4] = *(const float4*)(proto + (size_t)row * KFULL + k0 + s4 * 4);
    }
    __syncthreads();

#pragma unroll 4
    for (int k = 0; k < 128; k += 4) {
      float4 xa = *(float4*)&xl[n0][k];
      float4 xb = *(float4*)&xl[n0 + 8][k];
      float4 p0 = *(float4*)&pl[pb][k];
      float4 p1 = *(float4*)&pl[pb + 32][k];
      acc[0][0] += xa.x*p0.x + xa.y*p0.y + xa.z*p0.z + xa.w*p0.w;
      acc[0][1] += xa.x*p1.x + xa.y*p1.y + xa.z*p1.z + xa.w*p1.w;
      acc[1][0] += xb.x*p0.x + xb.y*p0.y + xb.z*p0.z + xb.w*p0.w;
      acc[1][1] += xb.x*p1.x + xb.y*p1.y + xb.z*p1.z + xb.w*p1.w;
    }
    if (t < 64) {
#pragma unroll 4
      for (int k = 0; k < 128; k += 4) {
        float4 pv = *(float4*)&pl[t][k];
        pn += pv.x*pv.x + pv.y*pv.y + pv.z*pv.z + pv.w*pv.w;
      }
    }
    __syncthreads();
  }

  atomicAdd(&dsum[n0 * 64 + pb],        -2.f * acc[0][0]);
  atomicAdd(&dsum[n0 * 64 + pb + 32],   -2.f * acc[0][1]);
  atomicAdd(&dsum[(n0+8) * 64 + pb],    -2.f * acc[1][0]);
  atomicAdd(&dsum[(n0+8) * 64 + pb+32], -2.f * acc[1][1]);
  if (t < 64) atomicAdd(&dsum[1024 + t], pn);
}

// ---------------------------------------------------------------------------
// select: rank-based, fully parallel. Block n (16 blocks x 64 lanes): lane p
// ranks its dist among all 64 (stable argsort order); rank<10 -> idx[n][rank].
// flags[] pre-zeroed by cvt_all; benign same-value race across blocks.
// ---------------------------------------------------------------------------
__global__ __launch_bounds__(64)
void select_kernel(const float* __restrict__ dsum, int* __restrict__ idx,
                   int* __restrict__ flags) {
  __shared__ float sh[64];
  const int n = blockIdx.x, t = threadIdx.x;
  float dval = dsum[1024 + t] + dsum[n * 64 + t];
  sh[t] = dval;
  __syncthreads();
  int rank = 0;
#pragma unroll
  for (int j = 0; j < 64; ++j) {
    float o = sh[j];
    rank += (o < dval || (o == dval && j < t)) ? 1 : 0;
  }
  if (rank < TOPK_) { idx[n * TOPK_ + rank] = t; flags[t] = 1; }
}

// ---------------------------------------------------------------------------
// bf16 MFMA GEMM, double-buffered, one barrier/iter. Tile 64Mx128Nx64K.
// 128 threads = 2 waves; wave-tile 64x64 = 4x4 of 16x16x32 (A reuse 4x).
// LDS k-quad-major: A cell(qk,m)=16B @ qk*1024B + m*16B; B cell(qk,n) =
// qk*2048B + n*16B. global_load_lds width=16, lane-contiguous by design.
// ---------------------------------------------------------------------------
#define BM 64
#define BKK 64

template <int MODE>
__global__ __launch_bounds__(128, 2)
void mfma_gemm_kernel(const unsigned short* __restrict__ Wb,
                      const unsigned short* __restrict__ Xb,
                      void* __restrict__ OutP,
                      const float* __restrict__ inputs,
                      const int* __restrict__ idxp,
                      const int* __restrict__ flags,
                      int K, int O, int Ldim) {
  __shared__ alignas(16) unsigned short Al[2][8 * BM * 8];    // 2 x 8 KB
  __shared__ alignas(16) unsigned short Bl[2][8 * 128 * 8];   // 2 x 16 KB
  __shared__ float nsum[2][64], nsq[2][64];
  __shared__ int ids[TOPK_];

  const int t = threadIdx.x;
  const int w = t >> 6;          // wave 0/1 -> n-half
  const int lane = t & 63;
  const int q = lane >> 4;
  const int l15 = lane & 15;
  const int batch = blockIdx.y;
  const int o0 = blockIdx.x * BM;

  if (MODE == 0 && flags && !flags[batch]) return;

  if (MODE == 1) {
    if (t < TOPK_) ids[t] = idxp[batch * TOPK_ + t];
    __syncthreads();
  }

  f32x4 acc[4][4] = {};

  auto issue = [&](int k0, int buf) {
    // A: wave w stages k-quads 4w..4w+3 (64 rows each, lane = m)
#pragma unroll
    for (int i = 0; i < 4; ++i) {
      int qk = w * 4 + i;
      const unsigned short* ga = Wb + (size_t)(o0 + lane) * K + k0 + qk * 8;
      __builtin_amdgcn_global_load_lds((const AS1 void*)ga,
                                       (AS3 void*)(&Al[buf][qk * 512]), 16, 0, 0);
    }
    const unsigned short* base; int rs;
    if (MODE == 1) {
      base = Xb + (size_t)ids[k0 >> 8] * (HW_ * RF_) + (k0 & 255);
      rs = RF_;
    } else {
      base = Xb + (size_t)batch * HW_ * K + k0;
      rs = K;
    }
    // B: wave w stages 8 of 16 (qk, half) regions
#pragma unroll
    for (int i = 0; i < 8; ++i) {
      int v = w * 8 + i;
      int qk = v >> 1, h = v & 1;
      const unsigned short* gb = base + (size_t)(h * 64 + lane) * rs + qk * 8;
      __builtin_amdgcn_global_load_lds((const AS1 void*)gb,
                                       (AS3 void*)(&Bl[buf][qk * 1024 + h * 512]), 16, 0, 0);
    }
  };

  issue(0, 0);
  __syncthreads();

  const int nIter = K / BKK;
  for (int it = 0; it < nIter; ++it) {
    const int buf = it & 1;
    if (it + 1 < nIter) issue((it + 1) * BKK, buf ^ 1);
#pragma unroll
    for (int s = 0; s < 2; ++s) {
      bf16x8 af[4], bfr[4];
#pragma unroll
      for (int mt = 0; mt < 4; ++mt)
        af[mt] = *(const bf16x8*)(&Al[buf][(s * 4 + q) * 512 + (mt * 16 + l15) * 8]);
#pragma unroll
      for (int nt = 0; nt < 4; ++nt)
        bfr[nt] = *(const bf16x8*)(&Bl[buf][(s * 4 + q) * 1024 + (w * 64 + nt * 16 + l15) * 8]);
#pragma unroll
      for (int mt = 0; mt < 4; ++mt)
#pragma unroll
        for (int nt = 0; nt < 4; ++nt)
          acc[mt][nt] = __builtin_amdgcn_mfma_f32_16x16x32_bf16(af[mt], bfr[nt], acc[mt][nt], 0, 0, 0);
    }
    __syncthreads();
  }

  // ---------------- epilogue ----------------
  const float CAL = 1.0f - 1.0f / 262144.0f;

  if (MODE == 2) {
#pragma unroll
    for (int mt = 0; mt < 4; ++mt)
#pragma unroll
      for (int reg = 0; reg < 4; ++reg) {
        float s_ = 0.f, q_ = 0.f;
#pragma unroll
        for (int nt = 0; nt < 4; ++nt) {
          float v = acc[mt][nt][reg];
          s_ += v; q_ += v * v;
        }
#pragma unroll
        for (int m = 1; m < 16; m <<= 1) {
          s_ += __shfl_xor(s_, m, 64);
          q_ += __shfl_xor(q_, m, 64);
        }
        if (l15 == 0) {
          int ol = mt * 16 + q * 4 + reg;
          nsum[w][ol] = s_; nsq[w][ol] = q_;
        }
      }
    __syncthreads();
  }

  if (MODE == 3) {
    float* ofb = (float*)OutP + (size_t)batch * DIM_ * HW_;
    const float* inb = inputs + (size_t)batch * DIM_ * HW_;
#pragma unroll
    for (int mt = 0; mt < 4; ++mt)
#pragma unroll
      for (int nt = 0; nt < 4; ++nt) {
        int o = o0 + mt * 16 + q * 4;
        int s = w * 64 + nt * 16 + l15;
        f32x4 v = acc[mt][nt];
#pragma unroll
        for (int g = 0; g < 4; ++g) {
          float in = inb[(size_t)(o + g) * HW_ + s];
          float sg = 1.f / (1.f + expf(-v[g]));
          ofb[(size_t)(o + g) * HW_ + s] = in * (1.f + sg);
        }
      }
  } else {
    unsigned short* ob = (unsigned short*)OutP + (size_t)batch * HW_ * Ldim;
    const float* inb = (MODE == 1) ? inputs + (size_t)batch * DIM_ * HW_ : nullptr;
#pragma unroll
    for (int mt = 0; mt < 4; ++mt) {
      float mean[4], rs[4];
      if (MODE == 2) {
#pragma unroll
        for (int reg = 0; reg < 4; ++reg) {
          int ol = mt * 16 + q * 4 + reg;
          float ts = nsum[0][ol] + nsum[1][ol];
          float tq = nsq[0][ol] + nsq[1][ol];
          float mn = ts * (1.f / 128.f);
          float vr = tq * (1.f / 128.f) - mn * mn;
          mean[reg] = mn; rs[reg] = rsqrtf(vr + 1e-5f);
        }
      }
#pragma unroll
      for (int nt = 0; nt < 4; ++nt) {
        int o = o0 + mt * 16 + q * 4;
        int s = w * 64 + nt * 16 + l15;
        f32x4 v = acc[mt][nt];
        float r[4];
        if (MODE == 0) {
#pragma unroll
          for (int g = 0; g < 4; ++g) r[g] = v[g];
        } else if (MODE == 1) {
          const float* ip = inb + (size_t)o * HW_ + s;
#pragma unroll
          for (int g = 0; g < 4; ++g)
            r[g] = fmaxf(0.f, 0.5f * ip[(size_t)g * HW_] + CAL * v[g]);
        } else {
#pragma unroll
          for (int g = 0; g < 4; ++g) r[g] = (v[g] - mean[g]) * rs[g];
        }
        ushort4 pk;
        pk.x = f2bf(r[0]); pk.y = f2bf(r[1]); pk.z = f2bf(r[2]); pk.w = f2bf(r[3]);
        *(ushort4*)(ob + (size_t)s * Ldim + o) = pk;
      }
    }
  }
}

// ---------------------------------------------------------------------------
extern "C" void kernel_launch(void* const* d_in, const int* in_sizes, int n_in,
                              void* d_out, int out_size, void* d_ws, size_t ws_size,
                              hipStream_t stream) {
  const float* inputs = (const float*)d_in[0];
  const float* proto  = (const float*)d_in[1];
  const float* w_rf   = (const float*)d_in[2];
  const float* w_rfmv = (const float*)d_in[3];
  const float* w_rms  = (const float*)d_in[4];
  const float* w_fuse = (const float*)d_in[5];
  float* out = (float*)d_out;

  uint8_t* ws = (uint8_t*)d_ws;
  size_t off = 0;
  auto alloc = [&](size_t bytes) { uint8_t* p = ws + off; off += (bytes + 255) & ~(size_t)255; return p; };

  float* dsum  = (float*)alloc(1088 * 4);       // 4352 B (256-aligned size)
  int*   flags = (int*)alloc(PN_ * 4);          // contiguous after dsum -> zeroed together
  int*   idx   = (int*)alloc(N_ * TOPK_ * 4);
  unsigned short* wrf_b   = (unsigned short*)alloc((size_t)RF_ * DIM_ * 2);
  unsigned short* wrfmv_b = (unsigned short*)alloc((size_t)DIM_ * KMV * 2);
  unsigned short* wrms_b  = (unsigned short*)alloc((size_t)DIM_ * DIM_ * 2);
  unsigned short* wfuse_b = (unsigned short*)alloc((size_t)DIM_ * DIM_ * 2);
  unsigned short* xpT     = (unsigned short*)alloc((size_t)PN_ * HW_ * RF_ * 2);
  unsigned short* protoT  = (unsigned short*)alloc((size_t)PN_ * HW_ * DIM_ * 2);
  unsigned short* mvlT = protoT;                 // aliases (protoT dead after G1)
  unsigned short* mvaT = protoT + (size_t)N_ * HW_ * DIM_;

  cvt_all_kernel<<<1024, 256, 0, stream>>>(w_rf, w_rfmv, w_rms, w_fuse,
                                           wrf_b, wrfmv_b, wrms_b, wfuse_b, dsum);
  transpose_proto_kernel<<<dim3(PN_, DIM_ / 32), 256, 0, stream>>>(proto, protoT);
  dist_partial_kernel<<<512, 256, 0, stream>>>(inputs, proto, dsum);
  select_kernel<<<N_, 64, 0, stream>>>(dsum, idx, flags);

  mfma_gemm_kernel<0><<<dim3(RF_ / BM, PN_), 128, 0, stream>>>(
      wrf_b, protoT, xpT, nullptr, nullptr, flags, DIM_, RF_, RF_);
  mfma_gemm_kernel<1><<<dim3(DIM_ / BM, N_), 128, 0, stream>>>(
      wrfmv_b, xpT, mvlT, inputs, idx, nullptr, KMV, DIM_, DIM_);
  mfma_gemm_kernel<2><<<dim3(DIM_ / BM, N_), 128, 0, stream>>>(
      wrms_b, mvlT, mvaT, nullptr, nullptr, nullptr, DIM_, DIM_, DIM_);
  mfma_gemm_kernel<3><<<dim3(DIM_ / BM, N_), 128, 0, stream>>>(
      wfuse_b, mvaT, out, inputs, nullptr, nullptr, DIM_, DIM_, DIM_);
}